// Round 1
// baseline (383.985 us; speedup 1.0000x reference)
//
#include <hip/hip_runtime.h>
#include <stdint.h>

// Problem sizes (fixed by reference)
constexpr int Bb = 8;      // batch
constexpr int Ss = 2048;   // sequence
constexpr int Dd = 1024;   // model dim (K of GEMM)
constexpr int Oo = 1024;   // expert out dim (N of GEMM)
constexpr int Ee = 8;      // experts

typedef __bf16 bf16x8 __attribute__((ext_vector_type(8)));
typedef float  f32x4  __attribute__((ext_vector_type(4)));

__device__ __forceinline__ unsigned short f2bf(float f) {
  // round-to-nearest-even fp32 -> bf16 (inputs are finite)
  unsigned int u = __float_as_uint(f);
  unsigned int r = (u + 0x7fffu + ((u >> 16) & 1u)) >> 16;
  return (unsigned short)r;
}

__device__ __forceinline__ void gl_lds16(const void* g, void* l) {
  // async 16B global -> LDS; LDS dest is wave-uniform base + lane*16
  __builtin_amdgcn_global_load_lds((const __attribute__((address_space(1))) void*)g,
                                   (__attribute__((address_space(3))) void*)l,
                                   16, 0, 0);
}

// ---------------------------------------------------------------------------
// Kernel A: convert x fp32->bf16 AND accumulate column sums (for mean pool)
// grid: (32, 8) blocks of 256; each block does 64 rows of one batch
// ---------------------------------------------------------------------------
__global__ __launch_bounds__(256) void k_convert_pool(
    const float* __restrict__ x, unsigned short* __restrict__ xb,
    float* __restrict__ pooled) {
  const int b  = blockIdx.y;
  const int sc = blockIdx.x;
  const int t  = threadIdx.x;
  const size_t base = (size_t)b * Ss * Dd + (size_t)sc * 64 * Dd + t * 4;
  const float4* xp = (const float4*)(x + base);
  ushort4* xo = (ushort4*)(xb + base);
  float4 acc = make_float4(0.f, 0.f, 0.f, 0.f);
#pragma unroll 4
  for (int s = 0; s < 64; ++s) {
    float4 v = xp[(size_t)s * (Dd / 4)];
    acc.x += v.x; acc.y += v.y; acc.z += v.z; acc.w += v.w;
    ushort4 o;
    o.x = f2bf(v.x); o.y = f2bf(v.y); o.z = f2bf(v.z); o.w = f2bf(v.w);
    xo[(size_t)s * (Dd / 4)] = o;
  }
  float* pd = pooled + b * Dd + t * 4;
  atomicAdd(pd + 0, acc.x);
  atomicAdd(pd + 1, acc.y);
  atomicAdd(pd + 2, acc.z);
  atomicAdd(pd + 3, acc.w);
}

// ---------------------------------------------------------------------------
// Kernel C: convert expert_w fp32->bf16. 8M elements, exactly covered.
// ---------------------------------------------------------------------------
__global__ __launch_bounds__(256) void k_convert_w(
    const float* __restrict__ w, unsigned short* __restrict__ wb) {
  size_t i = ((size_t)blockIdx.x * 256 + threadIdx.x) * 4;
  float4 v = *(const float4*)(w + i);
  ushort4 o;
  o.x = f2bf(v.x); o.y = f2bf(v.y); o.z = f2bf(v.z); o.w = f2bf(v.w);
  *(ushort4*)(wb + i) = o;
}

// ---------------------------------------------------------------------------
// Kernel B: logits = (pooled/S) @ gate_w^T + gate_b ; top-2 mask ; softmax
// One block, 256 threads. 4 threads per (b,e) pair.
// ---------------------------------------------------------------------------
__global__ __launch_bounds__(256) void k_gates(
    const float* __restrict__ pooled, const float* __restrict__ gw,
    const float* __restrict__ gb, float* __restrict__ gates) {
  __shared__ float slog[Bb * Ee];
  const int t = threadIdx.x;
  const int p = t >> 2, part = t & 3;
  const int b = p >> 3, e = p & 7;
  const float4* pv = (const float4*)(pooled + b * Dd + part * 256);
  const float4* wv = (const float4*)(gw + e * Dd + part * 256);
  float s = 0.f;
#pragma unroll
  for (int i = 0; i < 64; ++i) {
    float4 a = pv[i], w = wv[i];
    s += a.x * w.x + a.y * w.y + a.z * w.z + a.w * w.w;
  }
  s += __shfl_xor(s, 1);
  s += __shfl_xor(s, 2);
  if (part == 0) slog[p] = s * (1.0f / (float)Ss) + gb[e];
  __syncthreads();
  if (t < Bb) {
    float l[Ee];
    float m1 = -3.4e38f, m2 = -3.4e38f;
#pragma unroll
    for (int i = 0; i < Ee; ++i) {
      l[i] = slog[t * Ee + i];
      if (l[i] > m1) { m2 = m1; m1 = l[i]; }
      else if (l[i] > m2) m2 = l[i];
    }
    float den = 0.f;
    float ex[Ee];
#pragma unroll
    for (int i = 0; i < Ee; ++i) {
      ex[i] = (l[i] >= m2) ? expf(l[i] - m1) : 0.f;  // top-2 mask (handles ties)
      den += ex[i];
    }
#pragma unroll
    for (int i = 0; i < Ee; ++i) gates[t * Ee + i] = ex[i] / den;
  }
}

// ---------------------------------------------------------------------------
// Kernel D: per (S-tile, O-tile, b): for each active expert e (gate != 0),
// GEMM out_tile += gate * gelu(x[b] @ W[e]^T + bias[e]).
// 128x128 tile, BK=64, 4 waves (2x2), each wave 64x64 via 4x4 16x16x32 MFMAs.
// ---------------------------------------------------------------------------
constexpr int BM = 128, BN = 128, BK = 64;

__global__ __launch_bounds__(256) void k_moe_gemm(
    const unsigned short* __restrict__ xb, const unsigned short* __restrict__ wb,
    const float* __restrict__ gates, const float* __restrict__ expert_b,
    float* __restrict__ out) {
  __shared__ unsigned short sA[BM * BK];  // [128][64] bf16, linear
  __shared__ unsigned short sB[BN * BK];  // [128][64] bf16, linear

  const int m0 = blockIdx.x * BM;   // s
  const int n0 = blockIdx.y * BN;   // o
  const int b  = blockIdx.z;
  const int t  = threadIdx.x;
  const int lane = t & 63;
  const int wid  = t >> 6;
  const int wr = wid >> 1, wc = wid & 1;     // wave -> 64x64 subtile
  const int lr = lane & 15;                  // frag row (A) / col (B,D)
  const int lk = (lane >> 4) * 8;            // frag k elem offset

  // staging geometry: thread t stages 16B = 8 bf16 at linear byte t*16 (+r2*4096)
  const int srow = t >> 3;           // 0..31
  const int scol = (t & 7) * 8;      // 0..56
  const int ldsoff = wid * 1024;     // wave-uniform part of byte offset

  f32x4 fin[4][4] = {};

  for (int e = 0; e < Ee; ++e) {
    const float g = gates[b * Ee + e];
    if (g == 0.0f) continue;

    f32x4 acc[4][4] = {};
    const unsigned short* Abase = xb + (size_t)b * Ss * Dd + (size_t)m0 * Dd;
    const unsigned short* Bbase = wb + (size_t)e * Oo * Dd + (size_t)n0 * Dd;

    for (int kt = 0; kt < Dd; kt += BK) {
#pragma unroll
      for (int r2 = 0; r2 < 4; ++r2) {
        const int row = srow + r2 * 32;
        gl_lds16(Abase + (size_t)row * Dd + kt + scol,
                 (char*)sA + r2 * 4096 + ldsoff);
        gl_lds16(Bbase + (size_t)row * Dd + kt + scol,
                 (char*)sB + r2 * 4096 + ldsoff);
      }
      __syncthreads();  // compiler emits vmcnt(0) drain before barrier

#pragma unroll
      for (int ks = 0; ks < 2; ++ks) {
        bf16x8 af[4], bf[4];
#pragma unroll
        for (int m = 0; m < 4; ++m)
          af[m] = *(const bf16x8*)&sA[(wr * 64 + m * 16 + lr) * BK + ks * 32 + lk];
#pragma unroll
        for (int n = 0; n < 4; ++n)
          bf[n] = *(const bf16x8*)&sB[(wc * 64 + n * 16 + lr) * BK + ks * 32 + lk];
#pragma unroll
        for (int m = 0; m < 4; ++m)
#pragma unroll
          for (int n = 0; n < 4; ++n)
            acc[m][n] = __builtin_amdgcn_mfma_f32_16x16x32_bf16(
                af[m], bf[n], acc[m][n], 0, 0, 0);
      }
      __syncthreads();
    }

    // epilogue: bias + exact gelu + gate-weighted accumulate
#pragma unroll
    for (int n = 0; n < 4; ++n) {
      const int col = n0 + wc * 64 + n * 16 + lr;
      const float bias = expert_b[e * Oo + col];
#pragma unroll
      for (int m = 0; m < 4; ++m)
#pragma unroll
        for (int r = 0; r < 4; ++r) {
          const float v = acc[m][n][r] + bias;
          const float ge = 0.5f * v * (1.0f + erff(v * 0.70710678118654752f));
          fin[m][n][r] += g * ge;
        }
    }
  }

  // write out fp32
#pragma unroll
  for (int m = 0; m < 4; ++m)
#pragma unroll
    for (int r = 0; r < 4; ++r) {
      const int row = m0 + wr * 64 + m * 16 + (lane >> 4) * 4 + r;
      float* op = out + (size_t)b * Ss * Oo + (size_t)row * Oo + n0 + wc * 64 + lr;
#pragma unroll
      for (int n = 0; n < 4; ++n) op[n * 16] = fin[m][n][r];
    }
}

// ---------------------------------------------------------------------------
extern "C" void kernel_launch(void* const* d_in, const int* in_sizes, int n_in,
                              void* d_out, int out_size, void* d_ws, size_t ws_size,
                              hipStream_t stream) {
  const float* x        = (const float*)d_in[0];
  const float* gate_w   = (const float*)d_in[1];
  const float* gate_b   = (const float*)d_in[2];
  const float* expert_w = (const float*)d_in[3];
  const float* expert_b = (const float*)d_in[4];
  float* out = (float*)d_out;

  char* ws = (char*)d_ws;
  float* pooled = (float*)ws;                                   // B*D f32 = 32KB
  float* gates  = (float*)(ws + 32768);                         // B*E f32
  unsigned short* xb = (unsigned short*)(ws + 65536);           // B*S*D bf16 = 32MB
  unsigned short* wb = (unsigned short*)(ws + 65536 + (size_t)Bb * Ss * Dd * 2);  // 16MB

  hipMemsetAsync(pooled, 0, Bb * Dd * sizeof(float), stream);

  k_convert_pool<<<dim3(32, Bb), 256, 0, stream>>>(x, xb, pooled);
  k_convert_w<<<(Ee * Oo * Dd) / (256 * 4), 256, 0, stream>>>(expert_w, wb);
  k_gates<<<1, 256, 0, stream>>>(pooled, gate_w, gate_b, gates);
  k_moe_gemm<<<dim3(Ss / BM, Oo / BN, Bb), 256, 0, stream>>>(xb, wb, gates,
                                                             expert_b, out);
}

// Round 2
// 368.872 us; speedup vs baseline: 1.0410x; 1.0410x over previous
//
#include <hip/hip_runtime.h>
#include <stdint.h>

// Problem sizes (fixed by reference)
constexpr int Bb = 8;      // batch
constexpr int Ss = 2048;   // sequence
constexpr int Dd = 1024;   // model dim (K of GEMM)
constexpr int Oo = 1024;   // expert out dim (N of GEMM)
constexpr int Ee = 8;      // experts

typedef __bf16 bf16x8 __attribute__((ext_vector_type(8)));
typedef float  f32x4  __attribute__((ext_vector_type(4)));

__device__ __forceinline__ unsigned short f2bf(float f) {
  // round-to-nearest-even fp32 -> bf16 (inputs are finite)
  unsigned int u = __float_as_uint(f);
  unsigned int r = (u + 0x7fffu + ((u >> 16) & 1u)) >> 16;
  return (unsigned short)r;
}

__device__ __forceinline__ void gl_lds16(const void* g, void* l) {
  // async 16B global -> LDS; LDS dest is wave-uniform base + lane*16
  __builtin_amdgcn_global_load_lds((const __attribute__((address_space(1))) void*)g,
                                   (__attribute__((address_space(3))) void*)l,
                                   16, 0, 0);
}

// ---------------------------------------------------------------------------
// Kernel A: convert x fp32->bf16 AND accumulate column sums (for mean pool)
// grid: (256, 8) blocks of 256; each block does 8 rows of one batch
// ---------------------------------------------------------------------------
__global__ __launch_bounds__(256) void k_convert_pool(
    const float* __restrict__ x, unsigned short* __restrict__ xb,
    float* __restrict__ pooled) {
  const int b  = blockIdx.y;
  const int sc = blockIdx.x;
  const int t  = threadIdx.x;
  const size_t base = (size_t)b * Ss * Dd + (size_t)sc * 8 * Dd + t * 4;
  const float4* xp = (const float4*)(x + base);
  ushort4* xo = (ushort4*)(xb + base);
  float4 acc = make_float4(0.f, 0.f, 0.f, 0.f);
#pragma unroll
  for (int s = 0; s < 8; ++s) {
    float4 v = xp[(size_t)s * (Dd / 4)];
    acc.x += v.x; acc.y += v.y; acc.z += v.z; acc.w += v.w;
    ushort4 o;
    o.x = f2bf(v.x); o.y = f2bf(v.y); o.z = f2bf(v.z); o.w = f2bf(v.w);
    xo[(size_t)s * (Dd / 4)] = o;
  }
  float* pd = pooled + b * Dd + t * 4;
  atomicAdd(pd + 0, acc.x);
  atomicAdd(pd + 1, acc.y);
  atomicAdd(pd + 2, acc.z);
  atomicAdd(pd + 3, acc.w);
}

// ---------------------------------------------------------------------------
// Kernel C: convert expert_w fp32->bf16. 8M elements, exactly covered.
// ---------------------------------------------------------------------------
__global__ __launch_bounds__(256) void k_convert_w(
    const float* __restrict__ w, unsigned short* __restrict__ wb) {
  size_t i = ((size_t)blockIdx.x * 256 + threadIdx.x) * 4;
  float4 v = *(const float4*)(w + i);
  ushort4 o;
  o.x = f2bf(v.x); o.y = f2bf(v.y); o.z = f2bf(v.z); o.w = f2bf(v.w);
  *(ushort4*)(wb + i) = o;
}

// ---------------------------------------------------------------------------
// Kernel B: logits = (pooled/S) @ gate_w^T + gate_b ; top-2 mask ; softmax
// One block, 256 threads. 4 threads per (b,e) pair.
// ---------------------------------------------------------------------------
__global__ __launch_bounds__(256) void k_gates(
    const float* __restrict__ pooled, const float* __restrict__ gw,
    const float* __restrict__ gb, float* __restrict__ gates) {
  __shared__ float slog[Bb * Ee];
  const int t = threadIdx.x;
  const int p = t >> 2, part = t & 3;
  const int b = p >> 3, e = p & 7;
  const float4* pv = (const float4*)(pooled + b * Dd + part * 256);
  const float4* wv = (const float4*)(gw + e * Dd + part * 256);
  float s = 0.f;
#pragma unroll
  for (int i = 0; i < 64; ++i) {
    float4 a = pv[i], w = wv[i];
    s += a.x * w.x + a.y * w.y + a.z * w.z + a.w * w.w;
  }
  s += __shfl_xor(s, 1);
  s += __shfl_xor(s, 2);
  if (part == 0) slog[p] = s * (1.0f / (float)Ss) + gb[e];
  __syncthreads();
  if (t < Bb) {
    float l[Ee];
    float m1 = -3.4e38f, m2 = -3.4e38f;
#pragma unroll
    for (int i = 0; i < Ee; ++i) {
      l[i] = slog[t * Ee + i];
      if (l[i] > m1) { m2 = m1; m1 = l[i]; }
      else if (l[i] > m2) m2 = l[i];
    }
    float den = 0.f;
    float ex[Ee];
#pragma unroll
    for (int i = 0; i < Ee; ++i) {
      ex[i] = (l[i] >= m2) ? expf(l[i] - m1) : 0.f;  // top-2 mask (handles ties)
      den += ex[i];
    }
#pragma unroll
    for (int i = 0; i < Ee; ++i) gates[t * Ee + i] = ex[i] / den;
  }
}

// ---------------------------------------------------------------------------
// Kernel D: per (S-tile, O-tile, b): for each active expert e (gate != 0),
// GEMM tile = x[b] @ W[e]^T ; epilogue: out_tile (=: or +=) gate*gelu(tile+bias).
// No cross-expert register accumulator -> ~232 total regs -> 2 waves/SIMD.
// 128x128 tile, BK=64, 4 waves (2x2), each wave 64x64 via 4x4 16x16x32 MFMAs.
// ---------------------------------------------------------------------------
constexpr int BM = 128, BN = 128, BK = 64;

__global__ __launch_bounds__(256, 2) void k_moe_gemm(
    const unsigned short* __restrict__ xb, const unsigned short* __restrict__ wb,
    const float* __restrict__ gates, const float* __restrict__ expert_b,
    float* __restrict__ out) {
  __shared__ unsigned short sA[BM * BK];  // [128][64] bf16, linear
  __shared__ unsigned short sB[BN * BK];  // [128][64] bf16, linear

  const int m0 = blockIdx.x * BM;   // s
  const int n0 = blockIdx.y * BN;   // o
  const int b  = blockIdx.z;
  const int t  = threadIdx.x;
  const int lane = t & 63;
  const int wid  = t >> 6;
  const int wr = wid >> 1, wc = wid & 1;     // wave -> 64x64 subtile
  const int lr = lane & 15;                  // frag row (A) / col (B,D)
  const int lk = (lane >> 4) * 8;            // frag k elem offset

  // staging geometry: thread t stages 16B = 8 bf16 at linear byte t*16 (+r2*4096)
  const int srow = t >> 3;           // 0..31
  const int scol = (t & 7) * 8;      // 0..56
  const int ldsoff = wid * 1024;     // wave-uniform part of byte offset

  // hoist gates for this batch
  float gv[Ee];
#pragma unroll
  for (int e = 0; e < Ee; ++e) gv[e] = gates[b * Ee + e];

  bool first = true;

  for (int e = 0; e < Ee; ++e) {
    const float g = gv[e];
    if (g == 0.0f) continue;

    f32x4 acc[4][4] = {};
    const unsigned short* Abase = xb + (size_t)b * Ss * Dd + (size_t)m0 * Dd;
    const unsigned short* Bbase = wb + (size_t)e * Oo * Dd + (size_t)n0 * Dd;

    for (int kt = 0; kt < Dd; kt += BK) {
#pragma unroll
      for (int r2 = 0; r2 < 4; ++r2) {
        const int row = srow + r2 * 32;
        gl_lds16(Abase + (size_t)row * Dd + kt + scol,
                 (char*)sA + r2 * 4096 + ldsoff);
        gl_lds16(Bbase + (size_t)row * Dd + kt + scol,
                 (char*)sB + r2 * 4096 + ldsoff);
      }
      __syncthreads();  // compiler emits vmcnt(0) drain before barrier

#pragma unroll
      for (int ks = 0; ks < 2; ++ks) {
        bf16x8 af[4], bf[4];
#pragma unroll
        for (int m = 0; m < 4; ++m)
          af[m] = *(const bf16x8*)&sA[(wr * 64 + m * 16 + lr) * BK + ks * 32 + lk];
#pragma unroll
        for (int n = 0; n < 4; ++n)
          bf[n] = *(const bf16x8*)&sB[(wc * 64 + n * 16 + lr) * BK + ks * 32 + lk];
#pragma unroll
        for (int m = 0; m < 4; ++m)
#pragma unroll
          for (int n = 0; n < 4; ++n)
            acc[m][n] = __builtin_amdgcn_mfma_f32_16x16x32_bf16(
                af[m], bf[n], acc[m][n], 0, 0, 0);
      }
      __syncthreads();
    }

    // epilogue: bias + exact gelu + gate; first expert stores, later experts RMW
#pragma unroll
    for (int n = 0; n < 4; ++n) {
      const int col = n0 + wc * 64 + n * 16 + lr;
      const float bias = expert_b[e * Oo + col];
#pragma unroll
      for (int m = 0; m < 4; ++m)
#pragma unroll
        for (int r = 0; r < 4; ++r) {
          const int row = m0 + wr * 64 + m * 16 + (lane >> 4) * 4 + r;
          float* op = out + (size_t)b * Ss * Oo + (size_t)row * Oo + col;
          const float v = acc[m][n][r] + bias;
          const float ge = 0.5f * v * (1.0f + erff(v * 0.70710678118654752f));
          float val = g * ge;
          if (!first) val += *op;   // tile is L2-resident (same XCD wrote it)
          *op = val;
        }
    }
    first = false;
  }
}

// ---------------------------------------------------------------------------
extern "C" void kernel_launch(void* const* d_in, const int* in_sizes, int n_in,
                              void* d_out, int out_size, void* d_ws, size_t ws_size,
                              hipStream_t stream) {
  const float* x        = (const float*)d_in[0];
  const float* gate_w   = (const float*)d_in[1];
  const float* gate_b   = (const float*)d_in[2];
  const float* expert_w = (const float*)d_in[3];
  const float* expert_b = (const float*)d_in[4];
  float* out = (float*)d_out;

  char* ws = (char*)d_ws;
  float* pooled = (float*)ws;                                   // B*D f32 = 32KB
  float* gates  = (float*)(ws + 32768);                         // B*E f32
  unsigned short* xb = (unsigned short*)(ws + 65536);           // B*S*D bf16 = 32MB
  unsigned short* wb = (unsigned short*)(ws + 65536 + (size_t)Bb * Ss * Dd * 2);  // 16MB

  hipMemsetAsync(pooled, 0, Bb * Dd * sizeof(float), stream);

  k_convert_pool<<<dim3(256, Bb), 256, 0, stream>>>(x, xb, pooled);
  k_convert_w<<<(Ee * Oo * Dd) / (256 * 4), 256, 0, stream>>>(expert_w, wb);
  k_gates<<<1, 256, 0, stream>>>(pooled, gate_w, gate_b, gates);
  k_moe_gemm<<<dim3(Ss / BM, Oo / BN, Bb), 256, 0, stream>>>(xb, wb, gates,
                                                             expert_b, out);
}

// Round 3
// 272.201 us; speedup vs baseline: 1.4107x; 1.3551x over previous
//
#include <hip/hip_runtime.h>
#include <stdint.h>

// Problem sizes (fixed by reference)
constexpr int Bb = 8;      // batch
constexpr int Ss = 2048;   // sequence
constexpr int Dd = 1024;   // model dim (K of GEMM)
constexpr int Oo = 1024;   // expert out dim (N of GEMM)
constexpr int Ee = 8;      // experts

typedef __bf16 bf16x8 __attribute__((ext_vector_type(8)));
typedef float  f32x4  __attribute__((ext_vector_type(4)));

__device__ __forceinline__ unsigned short f2bf(float f) {
  // round-to-nearest-even fp32 -> bf16 (inputs are finite)
  unsigned int u = __float_as_uint(f);
  unsigned int r = (u + 0x7fffu + ((u >> 16) & 1u)) >> 16;
  return (unsigned short)r;
}

__device__ __forceinline__ void gl_lds16(const void* g, void* l) {
  // async 16B global -> LDS; LDS dest is wave-uniform base + lane*16
  __builtin_amdgcn_global_load_lds((const __attribute__((address_space(1))) void*)g,
                                   (__attribute__((address_space(3))) void*)l,
                                   16, 0, 0);
}

// ---------------------------------------------------------------------------
// Kernel A: convert x fp32->bf16 AND accumulate column sums (for mean pool)
// grid: (64, 8) blocks of 256; each block does 32 rows -> 64 atomics/address
// ---------------------------------------------------------------------------
__global__ __launch_bounds__(256) void k_convert_pool(
    const float* __restrict__ x, unsigned short* __restrict__ xb,
    float* __restrict__ pooled) {
  const int b  = blockIdx.y;
  const int sc = blockIdx.x;
  const int t  = threadIdx.x;
  const size_t base = (size_t)b * Ss * Dd + (size_t)sc * 32 * Dd + t * 4;
  const float4* xp = (const float4*)(x + base);
  ushort4* xo = (ushort4*)(xb + base);
  float4 acc = make_float4(0.f, 0.f, 0.f, 0.f);
#pragma unroll 8
  for (int s = 0; s < 32; ++s) {
    float4 v = xp[(size_t)s * (Dd / 4)];
    acc.x += v.x; acc.y += v.y; acc.z += v.z; acc.w += v.w;
    ushort4 o;
    o.x = f2bf(v.x); o.y = f2bf(v.y); o.z = f2bf(v.z); o.w = f2bf(v.w);
    xo[(size_t)s * (Dd / 4)] = o;
  }
  float* pd = pooled + b * Dd + t * 4;
  atomicAdd(pd + 0, acc.x);
  atomicAdd(pd + 1, acc.y);
  atomicAdd(pd + 2, acc.z);
  atomicAdd(pd + 3, acc.w);
}

// ---------------------------------------------------------------------------
// Kernel C: convert expert_w fp32->bf16. 8M elements, exactly covered.
// ---------------------------------------------------------------------------
__global__ __launch_bounds__(256) void k_convert_w(
    const float* __restrict__ w, unsigned short* __restrict__ wb) {
  size_t i = ((size_t)blockIdx.x * 256 + threadIdx.x) * 4;
  float4 v = *(const float4*)(w + i);
  ushort4 o;
  o.x = f2bf(v.x); o.y = f2bf(v.y); o.z = f2bf(v.z); o.w = f2bf(v.w);
  *(ushort4*)(wb + i) = o;
}

// ---------------------------------------------------------------------------
// Kernel B: logits = (pooled/S) @ gate_w^T + gate_b ; compact top-2 selection
// One block, 256 threads. 4 threads per (b,e) pair.
// Emits eidx[b][2] (expert ids) and egate[b][2] (softmax weights over top-2).
// ---------------------------------------------------------------------------
__global__ __launch_bounds__(256) void k_gates(
    const float* __restrict__ pooled, const float* __restrict__ gw,
    const float* __restrict__ gb, int* __restrict__ eidx,
    float* __restrict__ egate) {
  __shared__ float slog[Bb * Ee];
  const int t = threadIdx.x;
  const int p = t >> 2, part = t & 3;
  const int b = p >> 3, e = p & 7;
  const float4* pv = (const float4*)(pooled + b * Dd + part * 256);
  const float4* wv = (const float4*)(gw + e * Dd + part * 256);
  float s = 0.f;
#pragma unroll
  for (int i = 0; i < 64; ++i) {
    float4 a = pv[i], w = wv[i];
    s += a.x * w.x + a.y * w.y + a.z * w.z + a.w * w.w;
  }
  s += __shfl_xor(s, 1);
  s += __shfl_xor(s, 2);
  if (part == 0) slog[p] = s * (1.0f / (float)Ss) + gb[e];
  __syncthreads();
  if (t < Bb) {
    float m1 = -3.4e38f, m2 = -3.4e38f;
    int i1 = 0, i2 = 0;
#pragma unroll
    for (int i = 0; i < Ee; ++i) {
      const float v = slog[t * Ee + i];
      if (v > m1) { m2 = m1; i2 = i1; m1 = v; i1 = i; }
      else if (v > m2) { m2 = v; i2 = i; }
    }
    const float e2 = expf(m2 - m1);
    const float inv = 1.0f / (1.0f + e2);
    eidx[t * 2 + 0] = i1;
    eidx[t * 2 + 1] = i2;
    egate[t * 2 + 0] = inv;
    egate[t * 2 + 1] = e2 * inv;
  }
}

// ---------------------------------------------------------------------------
// Kernel D: fused dual-expert GEMM. Per (S-tile, O-tile, b): stage A once,
// B of BOTH active experts; 32 MFMA per ks phase into acc0/acc1; epilogue
// out = g0*gelu(acc0+b0) + g1*gelu(acc1+b1), single store (no RMW).
// LDS XOR-swizzle (16B units within each 128B row) via inverse-swizzled
// global source (linear gl_lds dest) + swizzled ds_read.
// 128x128 tile, BK=64, 4 waves (2x2), each wave 64x64 via 4x4 16x16x32 MFMAs.
// ---------------------------------------------------------------------------
constexpr int BM = 128, BN = 128, BK = 64;

__device__ __forceinline__ const bf16x8* frag_ptr(
    const unsigned short* s, int row, int unit_logical) {
  const int unit = unit_logical ^ (row & 7);
  return (const bf16x8*)((const char*)s + row * 128 + unit * 16);
}

__global__ __launch_bounds__(256, 2) void k_moe_gemm(
    const unsigned short* __restrict__ xb, const unsigned short* __restrict__ wb,
    const int* __restrict__ eidx, const float* __restrict__ egate,
    const float* __restrict__ expert_b, float* __restrict__ out) {
  __shared__ unsigned short sA[BM * BK];   // [128][64] bf16, 16KB
  __shared__ unsigned short sB0[BN * BK];  // 16KB
  __shared__ unsigned short sB1[BN * BK];  // 16KB

  // XCD-aware bijective swizzle: 1024 blocks, 8 XCDs -> one batch per XCD,
  // within-chunk x-fast so the B-panel (n0,e0,e1) stays L2-hot.
  const int hw = blockIdx.x;
  const int lg_id = ((hw & 7) << 7) | (hw >> 3);
  const int b  = lg_id >> 7;
  const int m0 = (lg_id & 15) * BM;         // s
  const int n0 = ((lg_id >> 4) & 7) * BN;   // o
  const int t  = threadIdx.x;
  const int lane = t & 63;
  const int wid  = t >> 6;
  const int wr = wid >> 1, wc = wid & 1;    // wave -> 64x64 subtile
  const int lr = lane & 15;                 // frag row (A) / col (B,D)
  const int lg = lane >> 4;                 // frag k-group 0..3

  const int e0 = eidx[b * 2 + 0];
  const int e1 = eidx[b * 2 + 1];
  const float g0 = egate[b * 2 + 0];
  const float g1 = egate[b * 2 + 1];

  // staging geometry: thread t writes LDS linear byte t*16 (+r2*4096);
  // global source column is inverse-swizzled so swizzled reads see logical data
  const int srow = t >> 3;                              // LDS row 0..31 (+r2*32)
  const int scol = (((t & 7) ^ (srow & 7)) * 8);        // element offset in row
  const int ldsoff = wid * 1024;                        // wave-uniform byte part

  f32x4 acc0[4][4] = {};
  f32x4 acc1[4][4] = {};

  const unsigned short* Abase  = xb + (size_t)b * Ss * Dd + (size_t)m0 * Dd;
  const unsigned short* B0base = wb + (size_t)e0 * Oo * Dd + (size_t)n0 * Dd;
  const unsigned short* B1base = wb + (size_t)e1 * Oo * Dd + (size_t)n0 * Dd;

  for (int kt = 0; kt < Dd; kt += BK) {
#pragma unroll
    for (int r2 = 0; r2 < 4; ++r2) {
      const int row = srow + r2 * 32;
      const size_t goff = (size_t)row * Dd + kt + scol;
      gl_lds16(Abase + goff,  (char*)sA  + r2 * 4096 + ldsoff);
      gl_lds16(B0base + goff, (char*)sB0 + r2 * 4096 + ldsoff);
      gl_lds16(B1base + goff, (char*)sB1 + r2 * 4096 + ldsoff);
    }
    __syncthreads();  // compiler emits vmcnt(0) drain before barrier

#pragma unroll
    for (int ks = 0; ks < 2; ++ks) {
      const int ul = (ks << 2) | lg;  // logical 16B unit within the 128B row
      bf16x8 af[4], bf0[4], bf1[4];
#pragma unroll
      for (int m = 0; m < 4; ++m)
        af[m] = *frag_ptr(sA, wr * 64 + m * 16 + lr, ul);
#pragma unroll
      for (int n = 0; n < 4; ++n) {
        bf0[n] = *frag_ptr(sB0, wc * 64 + n * 16 + lr, ul);
        bf1[n] = *frag_ptr(sB1, wc * 64 + n * 16 + lr, ul);
      }
#pragma unroll
      for (int m = 0; m < 4; ++m)
#pragma unroll
        for (int n = 0; n < 4; ++n) {
          acc0[m][n] = __builtin_amdgcn_mfma_f32_16x16x32_bf16(
              af[m], bf0[n], acc0[m][n], 0, 0, 0);
          acc1[m][n] = __builtin_amdgcn_mfma_f32_16x16x32_bf16(
              af[m], bf1[n], acc1[m][n], 0, 0, 0);
        }
    }
    __syncthreads();
  }

  // epilogue: out = g0*gelu(acc0+bias0) + g1*gelu(acc1+bias1), single store
#pragma unroll
  for (int n = 0; n < 4; ++n) {
    const int col = n0 + wc * 64 + n * 16 + lr;
    const float bias0 = expert_b[e0 * Oo + col];
    const float bias1 = expert_b[e1 * Oo + col];
#pragma unroll
    for (int m = 0; m < 4; ++m)
#pragma unroll
      for (int r = 0; r < 4; ++r) {
        const int row = m0 + wr * 64 + m * 16 + lg * 4 + r;
        const float v0 = acc0[m][n][r] + bias0;
        const float v1 = acc1[m][n][r] + bias1;
        const float ge0 = 0.5f * v0 * (1.0f + erff(v0 * 0.70710678118654752f));
        const float ge1 = 0.5f * v1 * (1.0f + erff(v1 * 0.70710678118654752f));
        out[(size_t)b * Ss * Oo + (size_t)row * Oo + col] = g0 * ge0 + g1 * ge1;
      }
  }
}

// ---------------------------------------------------------------------------
extern "C" void kernel_launch(void* const* d_in, const int* in_sizes, int n_in,
                              void* d_out, int out_size, void* d_ws, size_t ws_size,
                              hipStream_t stream) {
  const float* x        = (const float*)d_in[0];
  const float* gate_w   = (const float*)d_in[1];
  const float* gate_b   = (const float*)d_in[2];
  const float* expert_w = (const float*)d_in[3];
  const float* expert_b = (const float*)d_in[4];
  float* out = (float*)d_out;

  char* ws = (char*)d_ws;
  float* pooled = (float*)ws;                                   // B*D f32 = 32KB
  int*   eidx   = (int*)(ws + 32768);                           // B*2 ints
  float* egate  = (float*)(ws + 32768 + 4096);                  // B*2 floats
  unsigned short* xb = (unsigned short*)(ws + 65536);           // B*S*D bf16 = 32MB
  unsigned short* wb = (unsigned short*)(ws + 65536 + (size_t)Bb * Ss * Dd * 2);  // 16MB

  hipMemsetAsync(pooled, 0, Bb * Dd * sizeof(float), stream);

  k_convert_pool<<<dim3(64, Bb), 256, 0, stream>>>(x, xb, pooled);
  k_convert_w<<<(Ee * Oo * Dd) / (256 * 4), 256, 0, stream>>>(expert_w, wb);
  k_gates<<<1, 256, 0, stream>>>(pooled, gate_w, gate_b, eidx, egate);
  k_moe_gemm<<<(Ss / BM) * (Oo / BN) * Bb, 256, 0, stream>>>(xb, wb, eidx, egate,
                                                             expert_b, out);
}